// Round 7
// baseline (302.827 us; speedup 1.0000x reference)
//
#include <hip/hip_runtime.h>
#include <hip/hip_bf16.h>

// Problem constants: S=2048, B=32, He=Hd=1024, A=512, M = S*B = 65536.

typedef float f32x4 __attribute__((ext_vector_type(4)));
typedef __bf16 bf16x8 __attribute__((ext_vector_type(8)));

// workspace layout (bytes)
#define WS_DEC_OFF    0u                               // 32*512*4       = 65536
#define WS_WIMG_OFF   65536u                           // 32 chunks*32KB = 1048576
#define WS_PART_OFF   (65536u + 1048576u)              // 16*32*1024*4   = 2097152
#define WS_SPART_OFF  WS_PART_OFF                      // 4*32*2048*4 = 1MB, aliases
// (spart written by gemm, read by softmax BEFORE ctx_partial overwrites part)

// ---------------------------------------------------------------------------
// dec_att[b][a] = dot(dec_out[b,:], W_dec[a,:])   (32 x 512, K=1024)
__global__ void dec_att_kernel(const float* __restrict__ dec_out,
                               const float* __restrict__ W_dec,
                               float* __restrict__ out) {
  int gtid = blockIdx.x * blockDim.x + threadIdx.x;
  int w = gtid >> 6;
  int lane = gtid & 63;
  int b = w >> 9;          // 0..31
  int a = w & 511;         // 0..511
  const float4* dp = (const float4*)(dec_out + b * 1024);
  const float4* wp = (const float4*)(W_dec + a * 1024);
  float sum = 0.f;
#pragma unroll
  for (int i = 0; i < 4; ++i) {
    float4 x = dp[lane + i * 64];
    float4 y = wp[lane + i * 64];
    sum += x.x * y.x + x.y * y.y + x.z * y.z + x.w * y.w;
  }
#pragma unroll
  for (int m = 32; m; m >>= 1) sum += __shfl_xor(sum, m, 64);
  if (lane == 0) out[b * 512 + a] = sum;
}

// ---------------------------------------------------------------------------
// Pre-convert W_enc (512x1024 f32) into 32 K-chunk images, chunk kc =
// [512 rows][32 bf16] row-major (32 KB). The GEMM reads B fragments straight
// from this image (L2-resident) into registers.
__global__ void convert_wenc(const float* __restrict__ W, __bf16* __restrict__ out) {
  int idx = blockIdx.x * 256 + threadIdx.x;   // < 524288
  int kc = idx >> 14;
  int row = (idx >> 5) & 511;
  int j = idx & 31;
  out[idx] = (__bf16)W[row * 1024 + kc * 32 + j];
}

// ---------------------------------------------------------------------------
__device__ __forceinline__ bf16x8 cvt8(const float4& x, const float4& y) {
  bf16x8 v;
  v[0] = (__bf16)x.x; v[1] = (__bf16)x.y; v[2] = (__bf16)x.z; v[3] = (__bf16)x.w;
  v[4] = (__bf16)y.x; v[5] = (__bf16)y.y; v[6] = (__bf16)y.z; v[7] = (__bf16)y.w;
  return v;
}

// One K-step: cvt A(t) (f32 regs -> bf16 frags), issue A(t+1)/B(t+1) into the
// alternate named slots, run 16 MFMAs. No LDS, no barriers: the wave is a
// private software pipeline; the compiler emits counted vmcnt for the slots.
__device__ __forceinline__ void gstep(
    int t, const char* aptr, const char* bptr,
    float4& u00, float4& u01, float4& u10, float4& u11,   // A(t) f32 (use)
    float4& l00, float4& l01, float4& l10, float4& l11,   // A(t+1) f32 (load)
    bf16x8* bu, bf16x8* bl,                               // B(t) use / B(t+1) load
    f32x4 acc[2][8]) {
  bf16x8 af0 = cvt8(u00, u01);
  bf16x8 af1 = cvt8(u10, u11);
  const int tn = (t + 1 > 31) ? 31 : t + 1;   // clamped dummy on last step
  {
    const char* ap = aptr + tn * 128;
    l00 = *(const float4*)(ap);
    l01 = *(const float4*)(ap + 16);
    l10 = *(const float4*)(ap + 16 * 4096);
    l11 = *(const float4*)(ap + 16 * 4096 + 16);
    const char* bp = bptr + (size_t)tn * 32768;
#pragma unroll
    for (int nf = 0; nf < 8; ++nf)
      bl[nf] = *(const bf16x8*)(bp + nf * 1024);
  }
  __builtin_amdgcn_s_setprio(1);
#pragma unroll
  for (int nf = 0; nf < 8; ++nf) {
    acc[0][nf] = __builtin_amdgcn_mfma_f32_16x16x32_bf16(af0, bu[nf], acc[0][nf], 0, 0, 0);
    acc[1][nf] = __builtin_amdgcn_mfma_f32_16x16x32_bf16(af1, bu[nf], acc[1][nf], 0, 0, 0);
  }
  __builtin_amdgcn_s_setprio(0);
}

// ---------------------------------------------------------------------------
// scores GEMM: 1-wave blocks (64 thr), tile 32 rows x 128 cols, K=1024 in 32
// steps. A: global f32 -> regs -> bf16 (HBM, shared rows L2-hit via XCD
// swizzle). B: wimg (L2-resident) -> regs. acc 64 AGPR. Writes per-N-quarter
// partial scores; softmax sums the 4 slabs.
__global__ __launch_bounds__(64, 2) void scores_gemm(
    const float* __restrict__ enc,        // (65536, 1024) f32
    const __bf16* __restrict__ wimg,      // 32 chunks of [512][32] bf16
    const float* __restrict__ dec_att,    // [32][512] f32
    const float* __restrict__ attv,       // [512] f32
    float* __restrict__ spart) {          // [4][32][2048] f32 partial scores
  const int lane = threadIdx.x;
  const int q = lane >> 4;      // 0..3 (k-slot)
  const int c0 = lane & 15;
  // bijective XCD swizzle: d = (m>>3)*32 + (m&7) + nb*8  (d mod 8 == m mod 8,
  // so the 4 nb-blocks of one m-tile land on one XCD -> A rows L2-shared)
  const int d = blockIdx.x;     // 8192 blocks
  const int m = ((d >> 5) << 3) | (d & 7);   // 0..2047 (s index)
  const int nb = (d >> 3) & 3;               // N quarter

  f32x4 acc[2][8];
#pragma unroll
  for (int i = 0; i < 2; ++i)
#pragma unroll
    for (int j = 0; j < 8; ++j) acc[i][j] = (f32x4){0.f, 0.f, 0.f, 0.f};

  // A: row = m*32 + mf*16 + c0, k-bytes t*128 + q*32 (8 consecutive f32)
  const char* aptr = (const char*)enc + ((size_t)(m * 32 + c0)) * 4096 + q * 32;
  // B: row (n-col) = nb*128 + nf*16 + c0, byte q*16 within chunk; chunk t at
  // +t*32768, frag nf at +nf*1024
  const char* bptr = (const char*)wimg + (nb * 128 + c0) * 64 + q * 16;

  float4 aP00, aP01, aP10, aP11, aQ00, aQ01, aQ10, aQ11;
  bf16x8 bP[8], bQ[8];

  // prologue: A(0)->P, B(0)->bP
  {
    aP00 = *(const float4*)(aptr);
    aP01 = *(const float4*)(aptr + 16);
    aP10 = *(const float4*)(aptr + 16 * 4096);
    aP11 = *(const float4*)(aptr + 16 * 4096 + 16);
#pragma unroll
    for (int nf = 0; nf < 8; ++nf)
      bP[nf] = *(const bf16x8*)(bptr + nf * 1024);
  }

#pragma unroll 1
  for (int tt = 0; tt < 16; ++tt) {
    gstep(2 * tt,     aptr, bptr, aP00, aP01, aP10, aP11,
          aQ00, aQ01, aQ10, aQ11, bP, bQ, acc);
    gstep(2 * tt + 1, aptr, bptr, aQ00, aQ01, aQ10, aQ11,
          aP00, aP01, aP10, aP11, bQ, bP, acc);
  }

  // epilogue: C/D layout col = lane&15, row = q*4 + reg; local row rl == b
  float av[8];
#pragma unroll
  for (int nf = 0; nf < 8; ++nf) av[nf] = attv[nb * 128 + nf * 16 + c0];

#pragma unroll
  for (int mf = 0; mf < 2; ++mf) {
#pragma unroll
    for (int rg = 0; rg < 4; ++rg) {
      const int rl = mf * 16 + q * 4 + rg;   // 0..31 == batch index b
      const float* drow = dec_att + rl * 512 + nb * 128 + c0;
      float sum = 0.f;
#pragma unroll
      for (int nf = 0; nf < 8; ++nf) {
        float x = acc[mf][nf][rg] + drow[nf * 16];
        float e = __expf(2.f * x);           // tanh(x) = 1 - 2/(e^{2x}+1)
        float th = 1.f - 2.f / (e + 1.f);
        sum += th * av[nf];
      }
      sum += __shfl_xor(sum, 1, 64);
      sum += __shfl_xor(sum, 2, 64);
      sum += __shfl_xor(sum, 4, 64);
      sum += __shfl_xor(sum, 8, 64);
      if (c0 == 0) spart[nb * 65536 + rl * 2048 + m] = sum;
    }
  }
}

// ---------------------------------------------------------------------------
// softmax over S=2048 per batch row; sums the 4 N-quarter partial slabs first.
__global__ void softmax_kernel(const float* __restrict__ spart,
                               float* __restrict__ weights) {
  const int b = blockIdx.x;
  const int t = threadIdx.x;
  const float4* p0 = (const float4*)(spart + b * 2048);
  const float4* p1 = (const float4*)(spart + 65536 + b * 2048);
  const float4* p2 = (const float4*)(spart + 131072 + b * 2048);
  const float4* p3 = (const float4*)(spart + 196608 + b * 2048);
  float4 v0, v1;
  {
    float4 a0 = p0[t], a1 = p1[t], a2 = p2[t], a3 = p3[t];
    v0.x = a0.x + a1.x + a2.x + a3.x; v0.y = a0.y + a1.y + a2.y + a3.y;
    v0.z = a0.z + a1.z + a2.z + a3.z; v0.w = a0.w + a1.w + a2.w + a3.w;
    a0 = p0[t + 256]; a1 = p1[t + 256]; a2 = p2[t + 256]; a3 = p3[t + 256];
    v1.x = a0.x + a1.x + a2.x + a3.x; v1.y = a0.y + a1.y + a2.y + a3.y;
    v1.z = a0.z + a1.z + a2.z + a3.z; v1.w = a0.w + a1.w + a2.w + a3.w;
  }
  float mx = fmaxf(fmaxf(fmaxf(v0.x, v0.y), fmaxf(v0.z, v0.w)),
                   fmaxf(fmaxf(v1.x, v1.y), fmaxf(v1.z, v1.w)));
#pragma unroll
  for (int s = 32; s; s >>= 1) mx = fmaxf(mx, __shfl_xor(mx, s, 64));
  __shared__ float redm[4], reds[4];
  if ((t & 63) == 0) redm[t >> 6] = mx;
  __syncthreads();
  mx = fmaxf(fmaxf(redm[0], redm[1]), fmaxf(redm[2], redm[3]));
  float4 e0, e1;
  e0.x = __expf(v0.x - mx); e0.y = __expf(v0.y - mx);
  e0.z = __expf(v0.z - mx); e0.w = __expf(v0.w - mx);
  e1.x = __expf(v1.x - mx); e1.y = __expf(v1.y - mx);
  e1.z = __expf(v1.z - mx); e1.w = __expf(v1.w - mx);
  float s8 = e0.x + e0.y + e0.z + e0.w + e1.x + e1.y + e1.z + e1.w;
#pragma unroll
  for (int s = 32; s; s >>= 1) s8 += __shfl_xor(s8, s, 64);
  if ((t & 63) == 0) reds[t >> 6] = s8;
  __syncthreads();
  float inv = 1.f / (reds[0] + reds[1] + reds[2] + reds[3]);
  e0.x *= inv; e0.y *= inv; e0.z *= inv; e0.w *= inv;
  e1.x *= inv; e1.y *= inv; e1.z *= inv; e1.w *= inv;
  float4* wrow = (float4*)(weights + b * 2048);
  wrow[t] = e0;
  wrow[t + 256] = e1;
}

// ---------------------------------------------------------------------------
// context partials: block = (b, s-chunk of 128); thread owns float4 at h=t*4
__global__ void ctx_partial(const float* __restrict__ enc,
                            const float* __restrict__ weights,
                            float* __restrict__ part) {
  const int b = blockIdx.x & 31;
  const int sc = blockIdx.x >> 5;       // 0..15
  const int t = threadIdx.x;
  const float* wrow = weights + b * 2048 + sc * 128;
  const char* ebase = (const char*)(enc + ((size_t)(sc * 128) * 32 + b) * 1024) + t * 16;
  float4 acc = {0.f, 0.f, 0.f, 0.f};
#pragma unroll 4
  for (int i = 0; i < 128; ++i) {
    float4 e = *(const float4*)(ebase + (size_t)i * 131072);
    float ws = wrow[i];
    acc.x += ws * e.x; acc.y += ws * e.y; acc.z += ws * e.z; acc.w += ws * e.w;
  }
  *(float4*)(part + (size_t)(sc * 32 + b) * 1024 + t * 4) = acc;
}

__global__ void ctx_reduce(const float* __restrict__ part, float* __restrict__ ctx) {
  int idx = blockIdx.x * 256 + threadIdx.x;   // < 32768
  float s = 0.f;
#pragma unroll
  for (int c = 0; c < 16; ++c) s += part[c * 32768 + idx];
  ctx[idx] = s;
}

// ---------------------------------------------------------------------------
extern "C" void kernel_launch(void* const* d_in, const int* in_sizes, int n_in,
                              void* d_out, int out_size, void* d_ws, size_t ws_size,
                              hipStream_t stream) {
  const float* dec_out  = (const float*)d_in[0];   // (32, 1024)
  const float* enc_outs = (const float*)d_in[1];   // (2048, 32, 1024)
  const float* W_enc    = (const float*)d_in[2];   // (512, 1024)
  const float* W_dec    = (const float*)d_in[3];   // (512, 1024)
  const float* att_v    = (const float*)d_in[4];   // (512,)

  float* out = (float*)d_out;
  float* ctx = out;                 // (32,1024) = 32768 floats
  float* weights = out + 32768;     // (32,2048) = 65536 floats

  char* ws = (char*)d_ws;
  float*  ws_dec    = (float*)(ws + WS_DEC_OFF);
  __bf16* ws_wimg   = (__bf16*)(ws + WS_WIMG_OFF);
  float*  ws_spart  = (float*)(ws + WS_SPART_OFF);  // aliases ws_part (safe: read before part written)
  float*  ws_part   = (float*)(ws + WS_PART_OFF);

  dec_att_kernel<<<4096, 256, 0, stream>>>(dec_out, W_dec, ws_dec);
  convert_wenc<<<2048, 256, 0, stream>>>(W_enc, ws_wimg);
  scores_gemm<<<8192, 64, 0, stream>>>(enc_outs, ws_wimg, ws_dec, att_v, ws_spart);
  softmax_kernel<<<32, 256, 0, stream>>>(ws_spart, weights);
  ctx_partial<<<512, 256, 0, stream>>>(enc_outs, weights, ws_part);
  ctx_reduce<<<128, 256, 0, stream>>>(ws_part, ctx);
}

// Round 8
// 169.158 us; speedup vs baseline: 1.7902x; 1.7902x over previous
//
#include <hip/hip_runtime.h>
#include <hip/hip_bf16.h>

// Problem constants: S=2048, B=32, He=Hd=1024, A=512, M = S*B = 65536.

typedef float f32x4 __attribute__((ext_vector_type(4)));
typedef __bf16 bf16x8 __attribute__((ext_vector_type(8)));

// workspace layout (bytes)
#define WS_DEC_OFF    0u                               // 32*512*4       = 65536
#define WS_WIMG_OFF   65536u                           // 32 chunks*32KB = 1048576
#define WS_PART_OFF   (65536u + 1048576u)              // 16*32*1024*4   = 2097152
#define WS_SPART_OFF  WS_PART_OFF                      // 4*32*2048*4 = 1MB, aliases
// (spart written by gemm, read by softmax BEFORE ctx_partial overwrites part)

__device__ __forceinline__ void gload_lds16(const void* g, void* l) {
  __builtin_amdgcn_global_load_lds(
      (const __attribute__((address_space(1))) void*)g,
      (__attribute__((address_space(3))) void*)l, 16, 0, 0);
}

// ---------------------------------------------------------------------------
// dec_att[b][a] = dot(dec_out[b,:], W_dec[a,:])   (32 x 512, K=1024)
__global__ void dec_att_kernel(const float* __restrict__ dec_out,
                               const float* __restrict__ W_dec,
                               float* __restrict__ out) {
  int gtid = blockIdx.x * blockDim.x + threadIdx.x;
  int w = gtid >> 6;
  int lane = gtid & 63;
  int b = w >> 9;          // 0..31
  int a = w & 511;         // 0..511
  const float4* dp = (const float4*)(dec_out + b * 1024);
  const float4* wp = (const float4*)(W_dec + a * 1024);
  float sum = 0.f;
#pragma unroll
  for (int i = 0; i < 4; ++i) {
    float4 x = dp[lane + i * 64];
    float4 y = wp[lane + i * 64];
    sum += x.x * y.x + x.y * y.y + x.z * y.z + x.w * y.w;
  }
#pragma unroll
  for (int m = 32; m; m >>= 1) sum += __shfl_xor(sum, m, 64);
  if (lane == 0) out[b * 512 + a] = sum;
}

// ---------------------------------------------------------------------------
// Pre-convert W_enc (512x1024 f32) into 32 K-chunk images that ARE the GEMM's
// swizzled LDS image: chunk t, row n (0..511), 4 slots of 16B; logical slot j
// stored at s = j ^ (n&3). So GEMM B staging is a pure linear global_load_lds
// copy, and the swizzled ds_read_b128 is bank-conflict-free.
__global__ void convert_wenc(const float* __restrict__ W, __bf16* __restrict__ out) {
  int idx = blockIdx.x * 256 + threadIdx.x;   // < 524288
  int t = idx >> 14;          // k-chunk 0..31
  int r = (idx >> 5) & 511;   // n row
  int s = (idx >> 3) & 3;     // stored slot
  int e = idx & 7;            // element in slot
  out[idx] = (__bf16)W[r * 1024 + t * 32 + ((s ^ (r & 3)) << 3) + e];
}

// ---------------------------------------------------------------------------
// scores GEMM, m97 structure: BM=128, BN=128 (4 partial-score slabs over the
// a-dimension), BK=32, 256 threads = 4 waves in 2x2, wave tile 64x64
// (acc 4x4 f32x4 = 64 regs). Single LDS buffer, 2 barriers per K-step.
// A (f32, HBM): global_load_lds w16, linear dest + inverse-swizzled SOURCE
//   (slot j = (tid&7)^((tid>>3)&7)); read swizzled: slot L stored at L^(row&7).
// B (bf16 image, L2): linear copy of the pre-swizzled image.
// Epilogue: partial scores sum_a tanh(acc+dec)*av for this slab -> spart[nb].
__global__ __launch_bounds__(256, 2) void scores_gemm(
    const float* __restrict__ enc,        // (65536, 1024) f32
    const __bf16* __restrict__ wimg,      // 32 chunks, swizzled [512][4][16B]
    const float* __restrict__ dec_att,    // [32][512] f32
    const float* __restrict__ attv,       // [512] f32
    float* __restrict__ spart) {          // [4][32][2048] f32 partial scores
  // A: [128 rows][8 slots x 16B] f32 @0 (16KB); B: [128 rows][4 x 16B] bf16
  // @16384 (8KB); epart [128][2] f32 @24576 (1KB)
  __shared__ __align__(16) char smem[25600];

  const int tid = threadIdx.x;
  const int lane = tid & 63;
  const int w = tid >> 6;
  const int wr = w >> 1;        // M half
  const int wn = w & 1;         // N half
  const int q = lane >> 4;      // k-slot 0..3
  const int c0 = lane & 15;

  // XCD-aware mapping: the 4 nb-slabs of one bm land on one XCD (L2 A-reuse).
  const int xcd = blockIdx.x & 7;
  const int idx = blockIdx.x >> 3;       // 0..255
  const int bm = xcd + ((idx >> 2) << 3); // 0..511
  const int nb = idx & 3;                 // slab

  f32x4 acc[4][4];
#pragma unroll
  for (int i = 0; i < 4; ++i)
#pragma unroll
    for (int j = 0; j < 4; ++j) acc[i][j] = (f32x4){0.f, 0.f, 0.f, 0.f};

  // ---- A staging source (per-lane inverse-swizzle), dest = p*4096 + tid*16
  const int j_a = (tid & 7) ^ ((tid >> 3) & 7);
  const float* abase = enc + ((size_t)(bm * 128 + (tid >> 3))) * 1024 + j_a * 4;
  const char* bimg = (const char*)wimg;

  // ---- frag read offsets (swizzled)
  int a_off[4][2], b_off[4];
#pragma unroll
  for (int mf = 0; mf < 4; ++mf) {
    const int rl = wr * 64 + mf * 16 + c0;
#pragma unroll
    for (int j = 0; j < 2; ++j)
      a_off[mf][j] = rl * 128 + (((2 * q + j) ^ (rl & 7)) << 4);
  }
#pragma unroll
  for (int nf = 0; nf < 4; ++nf) {
    const int rn = wn * 64 + nf * 16 + c0;
    b_off[nf] = 16384 + rn * 64 + ((q ^ (rn & 3)) << 4);
  }

  // ---- K loop: stage -> barrier -> compute -> barrier (m97 schedule)
  for (int t = 0; t < 32; ++t) {
#pragma unroll
    for (int p = 0; p < 4; ++p)
      gload_lds16(abase + t * 32 + p * 32768, smem + p * 4096 + tid * 16);
    {
      const char* bs = bimg + (size_t)t * 32768 + nb * 8192 + tid * 16;
      gload_lds16(bs, smem + 16384 + tid * 16);
      gload_lds16(bs + 4096, smem + 16384 + 4096 + tid * 16);
    }
    __syncthreads();

    bf16x8 af[4], bfr[4];
#pragma unroll
    for (int mf = 0; mf < 4; ++mf) {
      f32x4 u0 = *(const f32x4*)(smem + a_off[mf][0]);
      f32x4 u1 = *(const f32x4*)(smem + a_off[mf][1]);
      bf16x8 v;
      v[0] = (__bf16)u0[0]; v[1] = (__bf16)u0[1]; v[2] = (__bf16)u0[2]; v[3] = (__bf16)u0[3];
      v[4] = (__bf16)u1[0]; v[5] = (__bf16)u1[1]; v[6] = (__bf16)u1[2]; v[7] = (__bf16)u1[3];
      af[mf] = v;
    }
#pragma unroll
    for (int nf = 0; nf < 4; ++nf) bfr[nf] = *(const bf16x8*)(smem + b_off[nf]);
#pragma unroll
    for (int mf = 0; mf < 4; ++mf)
#pragma unroll
      for (int nf = 0; nf < 4; ++nf)
        acc[mf][nf] = __builtin_amdgcn_mfma_f32_16x16x32_bf16(af[mf], bfr[nf],
                                                              acc[mf][nf], 0, 0, 0);
    __syncthreads();
  }

  // ---- epilogue: C/D layout col = lane&15, row = q*4 + reg
  float* epart = (float*)(smem + 24576);   // [128][2]
  float av[4];
#pragma unroll
  for (int nf = 0; nf < 4; ++nf) av[nf] = attv[nb * 128 + wn * 64 + nf * 16 + c0];

#pragma unroll
  for (int mf = 0; mf < 4; ++mf) {
#pragma unroll
    for (int rg = 0; rg < 4; ++rg) {
      const int rl = wr * 64 + mf * 16 + q * 4 + rg;   // local row 0..127
      const int b = rl & 31;                           // row = s*32+b
      const float* drow = dec_att + b * 512 + nb * 128 + wn * 64 + c0;
      float sum = 0.f;
#pragma unroll
      for (int nf = 0; nf < 4; ++nf) {
        float x = acc[mf][nf][rg] + drow[nf * 16];
        float e = __expf(2.f * x);                     // tanh(x) = 1 - 2/(e^{2x}+1)
        float th = 1.f - 2.f / (e + 1.f);
        sum += th * av[nf];
      }
      sum += __shfl_xor(sum, 1, 64);
      sum += __shfl_xor(sum, 2, 64);
      sum += __shfl_xor(sum, 4, 64);
      sum += __shfl_xor(sum, 8, 64);
      if (c0 == 0) epart[rl * 2 + wn] = sum;
    }
  }
  __syncthreads();
  if (tid < 128) {
    float tot = epart[tid * 2] + epart[tid * 2 + 1];
    // row r = bm*128 + tid ; s = bm*4 + (tid>>5), b = tid&31
    spart[nb * 65536 + (tid & 31) * 2048 + bm * 4 + (tid >> 5)] = tot;
  }
}

// ---------------------------------------------------------------------------
// softmax over S=2048 per batch row; sums the 4 N-slab partials first.
__global__ void softmax_kernel(const float* __restrict__ spart,
                               float* __restrict__ weights) {
  const int b = blockIdx.x;
  const int t = threadIdx.x;
  const float4* p0 = (const float4*)(spart + b * 2048);
  const float4* p1 = (const float4*)(spart + 65536 + b * 2048);
  const float4* p2 = (const float4*)(spart + 131072 + b * 2048);
  const float4* p3 = (const float4*)(spart + 196608 + b * 2048);
  float4 v0, v1;
  {
    float4 a0 = p0[t], a1 = p1[t], a2 = p2[t], a3 = p3[t];
    v0.x = a0.x + a1.x + a2.x + a3.x; v0.y = a0.y + a1.y + a2.y + a3.y;
    v0.z = a0.z + a1.z + a2.z + a3.z; v0.w = a0.w + a1.w + a2.w + a3.w;
    a0 = p0[t + 256]; a1 = p1[t + 256]; a2 = p2[t + 256]; a3 = p3[t + 256];
    v1.x = a0.x + a1.x + a2.x + a3.x; v1.y = a0.y + a1.y + a2.y + a3.y;
    v1.z = a0.z + a1.z + a2.z + a3.z; v1.w = a0.w + a1.w + a2.w + a3.w;
  }
  float mx = fmaxf(fmaxf(fmaxf(v0.x, v0.y), fmaxf(v0.z, v0.w)),
                   fmaxf(fmaxf(v1.x, v1.y), fmaxf(v1.z, v1.w)));
#pragma unroll
  for (int s = 32; s; s >>= 1) mx = fmaxf(mx, __shfl_xor(mx, s, 64));
  __shared__ float redm[4], reds[4];
  if ((t & 63) == 0) redm[t >> 6] = mx;
  __syncthreads();
  mx = fmaxf(fmaxf(redm[0], redm[1]), fmaxf(redm[2], redm[3]));
  float4 e0, e1;
  e0.x = __expf(v0.x - mx); e0.y = __expf(v0.y - mx);
  e0.z = __expf(v0.z - mx); e0.w = __expf(v0.w - mx);
  e1.x = __expf(v1.x - mx); e1.y = __expf(v1.y - mx);
  e1.z = __expf(v1.z - mx); e1.w = __expf(v1.w - mx);
  float s8 = e0.x + e0.y + e0.z + e0.w + e1.x + e1.y + e1.z + e1.w;
#pragma unroll
  for (int s = 32; s; s >>= 1) s8 += __shfl_xor(s8, s, 64);
  if ((t & 63) == 0) reds[t >> 6] = s8;
  __syncthreads();
  float inv = 1.f / (reds[0] + reds[1] + reds[2] + reds[3]);
  e0.x *= inv; e0.y *= inv; e0.z *= inv; e0.w *= inv;
  e1.x *= inv; e1.y *= inv; e1.z *= inv; e1.w *= inv;
  float4* wrow = (float4*)(weights + b * 2048);
  wrow[t] = e0;
  wrow[t + 256] = e1;
}

// ---------------------------------------------------------------------------
// context partials: block = (b, s-chunk of 128); thread owns float4 at h=t*4
__global__ void ctx_partial(const float* __restrict__ enc,
                            const float* __restrict__ weights,
                            float* __restrict__ part) {
  const int b = blockIdx.x & 31;
  const int sc = blockIdx.x >> 5;       // 0..15
  const int t = threadIdx.x;
  const float* wrow = weights + b * 2048 + sc * 128;
  const char* ebase = (const char*)(enc + ((size_t)(sc * 128) * 32 + b) * 1024) + t * 16;
  float4 acc = {0.f, 0.f, 0.f, 0.f};
#pragma unroll 4
  for (int i = 0; i < 128; ++i) {
    float4 e = *(const float4*)(ebase + (size_t)i * 131072);
    float ws = wrow[i];
    acc.x += ws * e.x; acc.y += ws * e.y; acc.z += ws * e.z; acc.w += ws * e.w;
  }
  *(float4*)(part + (size_t)(sc * 32 + b) * 1024 + t * 4) = acc;
}

__global__ void ctx_reduce(const float* __restrict__ part, float* __restrict__ ctx) {
  int idx = blockIdx.x * 256 + threadIdx.x;   // < 32768
  float s = 0.f;
#pragma unroll
  for (int c = 0; c < 16; ++c) s += part[c * 32768 + idx];
  ctx[idx] = s;
}

// ---------------------------------------------------------------------------
extern "C" void kernel_launch(void* const* d_in, const int* in_sizes, int n_in,
                              void* d_out, int out_size, void* d_ws, size_t ws_size,
                              hipStream_t stream) {
  const float* dec_out  = (const float*)d_in[0];   // (32, 1024)
  const float* enc_outs = (const float*)d_in[1];   // (2048, 32, 1024)
  const float* W_enc    = (const float*)d_in[2];   // (512, 1024)
  const float* W_dec    = (const float*)d_in[3];   // (512, 1024)
  const float* att_v    = (const float*)d_in[4];   // (512,)

  float* out = (float*)d_out;
  float* ctx = out;                 // (32,1024) = 32768 floats
  float* weights = out + 32768;     // (32,2048) = 65536 floats

  char* ws = (char*)d_ws;
  float*  ws_dec    = (float*)(ws + WS_DEC_OFF);
  __bf16* ws_wimg   = (__bf16*)(ws + WS_WIMG_OFF);
  float*  ws_spart  = (float*)(ws + WS_SPART_OFF);  // aliases ws_part (read before part written)
  float*  ws_part   = (float*)(ws + WS_PART_OFF);

  dec_att_kernel<<<4096, 256, 0, stream>>>(dec_out, W_dec, ws_dec);
  convert_wenc<<<2048, 256, 0, stream>>>(W_enc, ws_wimg);
  scores_gemm<<<2048, 256, 0, stream>>>(enc_outs, ws_wimg, ws_dec, att_v, ws_spart);
  softmax_kernel<<<32, 256, 0, stream>>>(ws_spart, weights);
  ctx_partial<<<512, 256, 0, stream>>>(enc_outs, weights, ws_part);
  ctx_reduce<<<128, 256, 0, stream>>>(ws_part, ctx);
}